// Round 1
// baseline (1131.472 us; speedup 1.0000x reference)
//
#include <hip/hip_runtime.h>
#include <math.h>

#define LL 4
#define NN 40000
#define DD 128
#define EE 320000
#define ROWS (LL*NN)         // 160000
#define ND (NN*DD)           // 5120000
#define EPS_LN 1e-5f

// ---------------- workspace layout (units of 4 bytes) ----------------
#define OFF_CNT      0                         // NN ints
#define OFF_ROWPTR   40000                     // NN+1 (padded to 40004)
#define OFF_ROWOFS   80004                     // NN
#define OFF_CCOLS    120004                    // EE
#define OFF_CVALS    440004                    // EE
#define OFF_A        760004                    // ROWS*DD   (16B aligned: 760004*4 % 16 == 0)
#define OFF_B        (OFF_A + ROWS*DD)
#define OFF_S        (OFF_B + ROWS*DD)
#define OFF_WTS      (OFF_S + ROWS*DD)         // ROWS floats

// ---------------- CSR build ----------------
__global__ void k_hist(const int* __restrict__ rows, int* __restrict__ cnt) {
    int e = blockIdx.x * 256 + threadIdx.x;
    if (e < EE) atomicAdd(&cnt[rows[e]], 1);
}

__global__ __launch_bounds__(1024) void k_scan(const int* __restrict__ cnt,
                                               int* __restrict__ row_ptr,
                                               int* __restrict__ row_ofs) {
    __shared__ int wtot[16];
    __shared__ int s_carry;
    int tid = threadIdx.x;
    int lane = tid & 63, wid = tid >> 6;
    if (tid == 0) s_carry = 0;
    __syncthreads();
    for (int base = 0; base <= NN; base += 1024) {
        int i = base + tid;
        int v = (i < NN) ? cnt[i] : 0;
        int incl = v;
        #pragma unroll
        for (int off = 1; off < 64; off <<= 1) {
            int t = __shfl_up(incl, off);
            if (lane >= off) incl += t;
        }
        if (lane == 63) wtot[wid] = incl;
        __syncthreads();
        if (wid == 0) {
            int w = (lane < 16) ? wtot[lane] : 0;
            #pragma unroll
            for (int off = 1; off < 16; off <<= 1) {
                int t = __shfl_up(w, off);
                if (lane >= off) w += t;
            }
            if (lane < 16) wtot[lane] = w;
        }
        __syncthreads();
        int carry = s_carry;
        int wofs = (wid > 0) ? wtot[wid - 1] : 0;
        int excl = carry + wofs + incl - v;
        if (i <= NN) {
            row_ptr[i] = excl;
            if (i < NN) row_ofs[i] = excl;
        }
        __syncthreads();
        if (tid == 0) s_carry = carry + wtot[15];
        __syncthreads();
    }
}

__global__ void k_scatter(const int* __restrict__ rows, const int* __restrict__ cols,
                          const float* __restrict__ vals, int* __restrict__ row_ofs,
                          int* __restrict__ csr_cols, float* __restrict__ csr_vals) {
    int e = blockIdx.x * 256 + threadIdx.x;
    if (e < EE) {
        int r = rows[e];
        int p = atomicAdd(&row_ofs[r], 1);
        csr_cols[p] = cols[e];
        csr_vals[p] = vals[e];
    }
}

// ---------------- SpMM: out[l,r,d] = sum_e vals[e] * in[l,cols[e],d] ----------------
// block = 128 threads, 1 block per row r; thread t handles float4 at (l = t>>5, d4 = (t&31)*4)
__global__ __launch_bounds__(128) void k_spmm(const float* __restrict__ in,
                                              const int* __restrict__ row_ptr,
                                              const int* __restrict__ ccols,
                                              const float* __restrict__ cvals,
                                              float* __restrict__ out) {
    int r = blockIdx.x;
    int tid = threadIdx.x;
    int l = tid >> 5;
    int d4 = (tid & 31) * 4;
    int ofs = l * ND + d4;
    float4 acc = make_float4(0.f, 0.f, 0.f, 0.f);
    int e0 = row_ptr[r], e1 = row_ptr[r + 1];
    for (int e = e0; e < e1; ++e) {
        int c = ccols[e];
        float v = cvals[e];
        float4 xv = *(const float4*)(in + ofs + c * DD);
        acc.x += v * xv.x; acc.y += v * xv.y; acc.z += v * xv.z; acc.w += v * xv.w;
    }
    *(float4*)(out + ofs + r * DD) = acc;
}

// ---------------- SAGE: S = silu(x @ W0 + b + agg @ W1) ----------------
// 2500 blocks x 256 threads; 64 rows/block; thread: cols (cg, cg+64), 16 rows
__global__ __launch_bounds__(256) void k_sage(const float* __restrict__ x,
                                              const float* __restrict__ agg,
                                              const float* __restrict__ W0,
                                              const float* __restrict__ W1,
                                              const float* __restrict__ bias,
                                              float* __restrict__ out) {
    __shared__ float ldsx[64 * 128];
    __shared__ float ldsa[64 * 128];
    int tid = threadIdx.x;
    int r0 = blockIdx.x * 64;
    {
        const float4* xp = (const float4*)(x + (size_t)r0 * 128);
        const float4* ap = (const float4*)(agg + (size_t)r0 * 128);
        float4* lx = (float4*)ldsx;
        float4* la = (float4*)ldsa;
        for (int i = tid; i < 2048; i += 256) { lx[i] = xp[i]; la[i] = ap[i]; }
    }
    __syncthreads();
    int cg = tid & 63, rg = tid >> 6;
    int c0 = cg, c1 = cg + 64;
    float acc0[16], acc1[16];
    float b0 = bias[c0], b1 = bias[c1];
    #pragma unroll
    for (int r = 0; r < 16; ++r) { acc0[r] = b0; acc1[r] = b1; }
    const float* lxr = ldsx + rg * 16 * 128;
    const float* lar = ldsa + rg * 16 * 128;
    for (int k0 = 0; k0 < 128; k0 += 4) {
        float w00[4], w01[4], w10[4], w11[4];
        #pragma unroll
        for (int kk = 0; kk < 4; ++kk) {
            w00[kk] = W0[(k0 + kk) * 128 + c0];
            w01[kk] = W0[(k0 + kk) * 128 + c1];
            w10[kk] = W1[(k0 + kk) * 128 + c0];
            w11[kk] = W1[(k0 + kk) * 128 + c1];
        }
        #pragma unroll
        for (int r = 0; r < 16; ++r) {
            float4 xa = *(const float4*)(lxr + r * 128 + k0);
            float4 aa = *(const float4*)(lar + r * 128 + k0);
            acc0[r] += xa.x*w00[0] + xa.y*w00[1] + xa.z*w00[2] + xa.w*w00[3]
                     + aa.x*w10[0] + aa.y*w10[1] + aa.z*w10[2] + aa.w*w10[3];
            acc1[r] += xa.x*w01[0] + xa.y*w01[1] + xa.z*w01[2] + xa.w*w01[3]
                     + aa.x*w11[0] + aa.y*w11[1] + aa.z*w11[2] + aa.w*w11[3];
        }
    }
    #pragma unroll
    for (int r = 0; r < 16; ++r) {
        int row = r0 + rg * 16 + r;
        float v0 = acc0[r], v1 = acc1[r];
        out[(size_t)row * 128 + c0] = v0 / (1.f + __expf(-v0));
        out[(size_t)row * 128 + c1] = v1 / (1.f + __expf(-v1));
    }
}

// ---------------- QK weights: wts[row] (+)= scale * (1/16) * sum_j (src@K)_j*(src@Q)_j ----------
// 2500 blocks x 256; 64 rows/block; cg = col in [0,32) (0-15 key, 16-31 query), rg: 8 rows each
__global__ __launch_bounds__(256) void k_qk(const float* __restrict__ src,
                                            const float* __restrict__ kW,
                                            const float* __restrict__ qW,
                                            float scale, int accumulate,
                                            float* __restrict__ wts) {
    __shared__ float lds[64 * 128];
    int tid = threadIdx.x;
    int r0 = blockIdx.x * 64;
    {
        const float4* sp = (const float4*)(src + (size_t)r0 * 128);
        float4* l4 = (float4*)lds;
        for (int i = tid; i < 2048; i += 256) l4[i] = sp[i];
    }
    __syncthreads();
    int cg = tid & 31, rg = tid >> 5;
    const float* Wp = (cg < 16) ? (kW + cg) : (qW + cg - 16);
    float acc[8];
    #pragma unroll
    for (int r = 0; r < 8; ++r) acc[r] = 0.f;
    const float* lr = lds + rg * 8 * 128;
    for (int k0 = 0; k0 < 128; k0 += 4) {
        float w[4];
        #pragma unroll
        for (int kk = 0; kk < 4; ++kk) w[kk] = Wp[(k0 + kk) * 16];
        #pragma unroll
        for (int r = 0; r < 8; ++r) {
            float4 a = *(const float4*)(lr + r * 128 + k0);
            acc[r] += a.x*w[0] + a.y*w[1] + a.z*w[2] + a.w*w[3];
        }
    }
    #pragma unroll
    for (int r = 0; r < 8; ++r) {
        float partner = __shfl_xor(acc[r], 16);
        float p = acc[r] * partner;               // kv_j * qv_j (appears twice per j)
        p += __shfl_xor(p, 1);
        p += __shfl_xor(p, 2);
        p += __shfl_xor(p, 4);
        p += __shfl_xor(p, 8);
        p += __shfl_xor(p, 16);                   // sum over the 32-lane half = 2*sum_j
        if (cg == 0) {
            int row = r0 + rg * 8 + r;
            float contrib = p * (scale * (1.f / 32.f));
            if (accumulate) wts[row] += contrib; else wts[row] = contrib;
        }
    }
}

// ---------------- value: out = ((x + 0.5A + 0.25B) @ Wv) * wts[row]  (out aliases A) -----------
__global__ __launch_bounds__(256) void k_value(const float* __restrict__ x,
                                               const float* __restrict__ A,
                                               const float* __restrict__ B,
                                               const float* __restrict__ Wv,
                                               const float* __restrict__ wts,
                                               float* __restrict__ out) {
    __shared__ float lds[64 * 128];
    int tid = threadIdx.x;
    int r0 = blockIdx.x * 64;
    {
        const float4* xp = (const float4*)(x + (size_t)r0 * 128);
        const float4* ap = (const float4*)(A + (size_t)r0 * 128);
        const float4* bp = (const float4*)(B + (size_t)r0 * 128);
        float4* l4 = (float4*)lds;
        for (int i = tid; i < 2048; i += 256) {
            float4 xa = xp[i], aa = ap[i], ba = bp[i];
            float4 o;
            o.x = xa.x + 0.5f*aa.x + 0.25f*ba.x;
            o.y = xa.y + 0.5f*aa.y + 0.25f*ba.y;
            o.z = xa.z + 0.5f*aa.z + 0.25f*ba.z;
            o.w = xa.w + 0.5f*aa.w + 0.25f*ba.w;
            l4[i] = o;
        }
    }
    __syncthreads();
    int cg = tid & 63, rg = tid >> 6;
    int c0 = cg, c1 = cg + 64;
    float acc0[16], acc1[16];
    #pragma unroll
    for (int r = 0; r < 16; ++r) { acc0[r] = 0.f; acc1[r] = 0.f; }
    const float* lr = lds + rg * 16 * 128;
    for (int k0 = 0; k0 < 128; k0 += 4) {
        float w0[4], w1[4];
        #pragma unroll
        for (int kk = 0; kk < 4; ++kk) {
            w0[kk] = Wv[(k0 + kk) * 128 + c0];
            w1[kk] = Wv[(k0 + kk) * 128 + c1];
        }
        #pragma unroll
        for (int r = 0; r < 16; ++r) {
            float4 a = *(const float4*)(lr + r * 128 + k0);
            acc0[r] += a.x*w0[0] + a.y*w0[1] + a.z*w0[2] + a.w*w0[3];
            acc1[r] += a.x*w1[0] + a.y*w1[1] + a.z*w1[2] + a.w*w1[3];
        }
    }
    #pragma unroll
    for (int r = 0; r < 16; ++r) {
        int row = r0 + rg * 16 + r;
        float wt = wts[row];
        out[(size_t)row * 128 + c0] = acc0[r] * wt;
        out[(size_t)row * 128 + c1] = acc1[r] * wt;
    }
}

// ---------------- final: out = silu((S + Attn) @ Wl + bl) ----------------
__global__ __launch_bounds__(256) void k_final(const float* __restrict__ S,
                                               const float* __restrict__ Attn,
                                               const float* __restrict__ Wl,
                                               const float* __restrict__ bl,
                                               float* __restrict__ out) {
    __shared__ float lds[64 * 128];
    int tid = threadIdx.x;
    int r0 = blockIdx.x * 64;
    {
        const float4* sp = (const float4*)(S + (size_t)r0 * 128);
        const float4* ap = (const float4*)(Attn + (size_t)r0 * 128);
        float4* l4 = (float4*)lds;
        for (int i = tid; i < 2048; i += 256) {
            float4 sa = sp[i], aa = ap[i];
            float4 o;
            o.x = sa.x + aa.x; o.y = sa.y + aa.y; o.z = sa.z + aa.z; o.w = sa.w + aa.w;
            l4[i] = o;
        }
    }
    __syncthreads();
    int cg = tid & 63, rg = tid >> 6;
    int c0 = cg, c1 = cg + 64;
    float acc0[16], acc1[16];
    float b0 = bl[c0], b1 = bl[c1];
    #pragma unroll
    for (int r = 0; r < 16; ++r) { acc0[r] = b0; acc1[r] = b1; }
    const float* lr = lds + rg * 16 * 128;
    for (int k0 = 0; k0 < 128; k0 += 4) {
        float w0[4], w1[4];
        #pragma unroll
        for (int kk = 0; kk < 4; ++kk) {
            w0[kk] = Wl[(k0 + kk) * 128 + c0];
            w1[kk] = Wl[(k0 + kk) * 128 + c1];
        }
        #pragma unroll
        for (int r = 0; r < 16; ++r) {
            float4 a = *(const float4*)(lr + r * 128 + k0);
            acc0[r] += a.x*w0[0] + a.y*w0[1] + a.z*w0[2] + a.w*w0[3];
            acc1[r] += a.x*w1[0] + a.y*w1[1] + a.z*w1[2] + a.w*w1[3];
        }
    }
    #pragma unroll
    for (int r = 0; r < 16; ++r) {
        int row = r0 + rg * 16 + r;
        float v0 = acc0[r], v1 = acc1[r];
        out[(size_t)row * 128 + c0] = v0 / (1.f + __expf(-v0));
        out[(size_t)row * 128 + c1] = v1 / (1.f + __expf(-v1));
    }
}

// ---------------- layernorm over D=128, one wave per row ----------------
__global__ __launch_bounds__(256) void k_ln(const float* __restrict__ in,
                                            const float* __restrict__ g,
                                            const float* __restrict__ b,
                                            float* __restrict__ out) {
    int row = blockIdx.x * 4 + (threadIdx.x >> 6);
    int lane = threadIdx.x & 63;
    const float2* ip = (const float2*)(in + (size_t)row * 128);
    float2 v = ip[lane];
    float s = v.x + v.y;
    float sq = v.x * v.x + v.y * v.y;
    #pragma unroll
    for (int off = 32; off; off >>= 1) {
        s += __shfl_xor(s, off);
        sq += __shfl_xor(sq, off);
    }
    float mu = s * (1.f / 128.f);
    float var = sq * (1.f / 128.f) - mu * mu;
    float rs = rsqrtf(var + EPS_LN);
    float2 gg = ((const float2*)g)[lane];
    float2 bb = ((const float2*)b)[lane];
    float2 o;
    o.x = (v.x - mu) * rs * gg.x + bb.x;
    o.y = (v.y - mu) * rs * gg.y + bb.y;
    ((float2*)(out + (size_t)row * 128))[lane] = o;
}

extern "C" void kernel_launch(void* const* d_in, const int* in_sizes, int n_in,
                              void* d_out, int out_size, void* d_ws, size_t ws_size,
                              hipStream_t stream) {
    const float* x       = (const float*)d_in[0];
    const int*   erows   = (const int*)d_in[1];
    const int*   ecols   = (const int*)d_in[2];
    const float* evals   = (const float*)d_in[3];
    const float* sage_W  = (const float*)d_in[4];
    const float* sage_b  = (const float*)d_in[5];
    const float* sage_aW = (const float*)d_in[6];
    const float* key_W   = (const float*)d_in[7];
    const float* query_W = (const float*)d_in[8];
    const float* value_W = (const float*)d_in[9];
    const float* attn_g  = (const float*)d_in[10];
    const float* attn_b  = (const float*)d_in[11];
    const float* lin_W   = (const float*)d_in[12];
    const float* lin_b   = (const float*)d_in[13];
    const float* ln_g    = (const float*)d_in[14];
    const float* ln_b    = (const float*)d_in[15];
    float* out = (float*)d_out;

    int*   wsi = (int*)d_ws;
    float* wsf = (float*)d_ws;
    int*   cnt      = wsi + OFF_CNT;
    int*   row_ptr  = wsi + OFF_ROWPTR;
    int*   row_ofs  = wsi + OFF_ROWOFS;
    int*   csr_cols = wsi + OFF_CCOLS;
    float* csr_vals = wsf + OFF_CVALS;
    float* A   = wsf + OFF_A;   // agg  -> later attn_out (in-place)
    float* B   = wsf + OFF_B;   // agg2 -> later pre-LN final
    float* S   = wsf + OFF_S;   // sage_out
    float* WTS = wsf + OFF_WTS;

    // CSR build (re-done every call; ws is poisoned before each timed launch)
    hipMemsetAsync(cnt, 0, NN * sizeof(int), stream);
    k_hist<<<(EE + 255) / 256, 256, 0, stream>>>(erows, cnt);
    k_scan<<<1, 1024, 0, stream>>>(cnt, row_ptr, row_ofs);
    k_scatter<<<(EE + 255) / 256, 256, 0, stream>>>(erows, ecols, evals, row_ofs, csr_cols, csr_vals);

    // A = spmm(x); B = spmm(A)    (cur1 = 0.5*A, cur2 = 0.25*B by linearity)
    k_spmm<<<NN, 128, 0, stream>>>(x, row_ptr, csr_cols, csr_vals, A);
    k_spmm<<<NN, 128, 0, stream>>>(A, row_ptr, csr_cols, csr_vals, B);

    // sage_out = silu(x@sage_W + sage_b + A@sage_agg_W)
    k_sage<<<ROWS / 64, 256, 0, stream>>>(x, A, sage_W, sage_aW, sage_b, S);

    // weights = qk(x) + 0.25*qk(A) + 0.0625*qk(B)
    k_qk<<<ROWS / 64, 256, 0, stream>>>(x, key_W, query_W, 1.f,     0, WTS);
    k_qk<<<ROWS / 64, 256, 0, stream>>>(A, key_W, query_W, 0.25f,   1, WTS);
    k_qk<<<ROWS / 64, 256, 0, stream>>>(B, key_W, query_W, 0.0625f, 1, WTS);

    // attn (pre-LN) = ((x + 0.5A + 0.25B) @ value_W) * weights   -> overwrite A
    k_value<<<ROWS / 64, 256, 0, stream>>>(x, A, B, value_W, WTS, A);
    // attn_out = LN(attn)   in-place
    k_ln<<<ROWS / 4, 256, 0, stream>>>(A, attn_g, attn_b, A);

    // y = silu((sage_out + attn_out) @ lin_W + lin_b)  -> B
    k_final<<<ROWS / 64, 256, 0, stream>>>(S, A, lin_W, lin_b, B);
    // out = LN(y)
    k_ln<<<ROWS / 4, 256, 0, stream>>>(B, ln_g, ln_b, out);
}

// Round 5
// 856.857 us; speedup vs baseline: 1.3205x; 1.3205x over previous
//
#include <hip/hip_runtime.h>
#include <math.h>

#define LL 4
#define NN 40000
#define DD 128
#define EE 320000
#define ROWS (LL*NN)         // 160000
#define ND (NN*DD)           // 5120000
#define EPS_LN 1e-5f

typedef __attribute__((ext_vector_type(8))) short bf16x8;
typedef __attribute__((ext_vector_type(4))) float f32x4;

// ---------------- workspace layout (units of 4 bytes) ----------------
#define OFF_CNT      0                         // NN ints
#define OFF_ROWPTR   40000                     // NN+1
#define OFF_ROWOFS   80004                     // NN
#define OFF_CCOLS    120004                    // EE
#define OFF_CVALS    440004                    // EE
#define OFF_WBF      760004                    // bf16 hi/lo weights (139264 shorts)
#define OFF_A        829636                    // ROWS*DD floats (16B aligned)
#define OFF_B        (OFF_A + ROWS*DD)
#define OFF_Z        (OFF_B + ROWS*DD)         // ROWS*DD floats

// weight sub-offsets in SHORTS within WBF region. Each big matrix: 16384 hi then 16384 lo.
#define WB_W0  0        // sage_W^T      [n][k] 128x128
#define WB_W1  32768    // sage_agg_W^T
#define WB_WV  65536    // value_W^T
#define WB_WL  98304    // lin_W^T
#define WB_K   131072   // key_W^T   [16][128]: 2048 hi then 2048 lo
#define WB_Q   135168   // query_W^T
#define WB_LO_BIG 16384
#define WB_LO_KQ  2048
#define WB_LOGICAL 69632

__device__ __forceinline__ short f2bf(float f) {
    union { float f; unsigned u; } v; v.f = f;
    unsigned r = v.u + 0x7fffu + ((v.u >> 16) & 1u);   // RNE
    return (short)(r >> 16);
}
__device__ __forceinline__ float bf2f(short h) {
    union { unsigned u; float f; } v;
    v.u = ((unsigned)(unsigned short)h) << 16;
    return v.f;
}
__device__ __forceinline__ void splitbf(float v, short& h, short& l) {
    h = f2bf(v);
    l = f2bf(v - bf2f(h));
}

// ---------------- CSR build ----------------
__global__ void k_hist(const int* __restrict__ rows, int* __restrict__ cnt) {
    int e = blockIdx.x * 256 + threadIdx.x;
    if (e < EE) atomicAdd(&cnt[rows[e]], 1);
}

__global__ __launch_bounds__(1024) void k_scan(const int* __restrict__ cnt,
                                               int* __restrict__ row_ptr,
                                               int* __restrict__ row_ofs) {
    __shared__ int wtot[16];
    __shared__ int s_carry;
    int tid = threadIdx.x;
    int lane = tid & 63, wid = tid >> 6;
    if (tid == 0) s_carry = 0;
    __syncthreads();
    for (int base = 0; base <= NN; base += 1024) {
        int i = base + tid;
        int v = (i < NN) ? cnt[i] : 0;
        int incl = v;
        #pragma unroll
        for (int off = 1; off < 64; off <<= 1) {
            int t = __shfl_up(incl, off);
            if (lane >= off) incl += t;
        }
        if (lane == 63) wtot[wid] = incl;
        __syncthreads();
        if (wid == 0) {
            int w = (lane < 16) ? wtot[lane] : 0;
            #pragma unroll
            for (int off = 1; off < 16; off <<= 1) {
                int t = __shfl_up(w, off);
                if (lane >= off) w += t;
            }
            if (lane < 16) wtot[lane] = w;
        }
        __syncthreads();
        int carry = s_carry;
        int wofs = (wid > 0) ? wtot[wid - 1] : 0;
        int excl = carry + wofs + incl - v;
        if (i <= NN) {
            row_ptr[i] = excl;
            if (i < NN) row_ofs[i] = excl;
        }
        __syncthreads();
        if (tid == 0) s_carry = carry + wtot[15];
        __syncthreads();
    }
}

__global__ void k_scatter(const int* __restrict__ rows, const int* __restrict__ cols,
                          const float* __restrict__ vals, int* __restrict__ row_ofs,
                          int* __restrict__ csr_cols, float* __restrict__ csr_vals) {
    int e = blockIdx.x * 256 + threadIdx.x;
    if (e < EE) {
        int r = rows[e];
        int p = atomicAdd(&row_ofs[r], 1);
        csr_cols[p] = cols[e];
        csr_vals[p] = vals[e];
    }
}

// ---------------- SpMM: out[l,r,d] = sum_e vals[e] * in[l,cols[e],d] ----------------
__global__ __launch_bounds__(128) void k_spmm(const float* __restrict__ in,
                                              const int* __restrict__ row_ptr,
                                              const int* __restrict__ ccols,
                                              const float* __restrict__ cvals,
                                              float* __restrict__ out) {
    int r = blockIdx.x;
    int tid = threadIdx.x;
    int l = tid >> 5;
    int d4 = (tid & 31) * 4;
    int ofs = l * ND + d4;
    float4 acc = make_float4(0.f, 0.f, 0.f, 0.f);
    int e0 = row_ptr[r], e1 = row_ptr[r + 1];
    for (int e = e0; e < e1; ++e) {
        int c = ccols[e];
        float v = cvals[e];
        float4 xv = *(const float4*)(in + ofs + c * DD);
        acc.x += v * xv.x; acc.y += v * xv.y; acc.z += v * xv.z; acc.w += v * xv.w;
    }
    *(float4*)(out + ofs + r * DD) = acc;
}

// ---------------- weight prep: fp32 [k][n] -> bf16 hi/lo transposed [n][k] ----------------
__global__ void k_prep(const float* __restrict__ W0, const float* __restrict__ W1,
                       const float* __restrict__ Wv, const float* __restrict__ Wl,
                       const float* __restrict__ Kw, const float* __restrict__ Qw,
                       short* __restrict__ o) {
    int t = blockIdx.x * 256 + threadIdx.x;
    if (t >= WB_LOGICAL) return;
    float v;
    int hi_idx, lo_idx;
    if (t < 65536) {
        int m = t >> 14, idx = t & 16383;
        int nn = idx >> 7, kk = idx & 127;
        const float* M = (m == 0) ? W0 : (m == 1) ? W1 : (m == 2) ? Wv : Wl;
        v = M[kk * 128 + nn];
        hi_idx = m * 32768 + idx;
        lo_idx = hi_idx + WB_LO_BIG;
    } else {
        int t2 = t - 65536;
        int sel = t2 >> 11;
        int idx = t2 & 2047;
        int nn = idx >> 7, kk = idx & 127;
        const float* M = sel ? Qw : Kw;
        v = M[kk * 16 + nn];
        hi_idx = WB_K + sel * 4096 + idx;
        lo_idx = hi_idx + WB_LO_KQ;
    }
    short h, l;
    splitbf(v, h, l);
    o[hi_idx] = h;
    o[lo_idx] = l;
}

// ============ dense stage, kernel 1: qk + sage + value(+LN) -> Z ============
// 2500 blocks x 256 (4 waves); wave w owns rows blk*64 + w*16 .. +16.
// MFMA 16x16x32 bf16 (m89-verified):
//   A-frag: lane holds row m=lane&15, k=(lane>>4)*8+j   B-frag: col n=lane&15, same k
//   C/D:    col = lane&15, row = (lane>>4)*4 + reg
// Split-bf16: dot(a,b) ~= ah.bh + ah.bl + al.bh  (rel err ~2^-16; exact enough that
// wts never flips sign vs fp32 — LN(V*wts) amplifies wts sign only).
#define MFMA(a, b, c) __builtin_amdgcn_mfma_f32_16x16x32_bf16(a, b, c, 0, 0, 0)

__global__ __launch_bounds__(256) void k_dense1(
    const float* __restrict__ x, const float* __restrict__ A, const float* __restrict__ B,
    const short* __restrict__ wbf,
    const float* __restrict__ sage_b, const float* __restrict__ attn_g,
    const float* __restrict__ attn_b,
    float* __restrict__ Z)
{
    const int tid = threadIdx.x;
    const int w = tid >> 6;
    const int lane = tid & 63;
    const int n = lane & 15;
    const int q = lane >> 4;
    const size_t rowA = (size_t)blockIdx.x * 64 + w * 16 + n;

    // ---- interleaved load + split: x, A, B hi/lo frags + c fp32 (c = x+0.5A+0.25B) ----
    bf16x8 xh[4], xl[4], ah[4], al[4], bh[4], bl[4];
    f32x4 c0v[4], c1v[4];
    {
        const float* xp = x + rowA * 128 + q * 8;
        const float* ap = A + rowA * 128 + q * 8;
        const float* bp = B + rowA * 128 + q * 8;
        #pragma unroll
        for (int s = 0; s < 4; ++s) {
            f32x4 x0 = *(const f32x4*)(xp + s * 32);
            f32x4 x1 = *(const f32x4*)(xp + s * 32 + 4);
            f32x4 a0 = *(const f32x4*)(ap + s * 32);
            f32x4 a1 = *(const f32x4*)(ap + s * 32 + 4);
            f32x4 b0 = *(const f32x4*)(bp + s * 32);
            f32x4 b1 = *(const f32x4*)(bp + s * 32 + 4);
            c0v[s] = x0 + 0.5f * a0 + 0.25f * b0;
            c1v[s] = x1 + 0.5f * a1 + 0.25f * b1;
            #pragma unroll
            for (int i = 0; i < 4; ++i) {
                short h, l;
                splitbf(x0[i], h, l); xh[s][i] = h;     xl[s][i] = l;
                splitbf(x1[i], h, l); xh[s][i + 4] = h; xl[s][i + 4] = l;
                splitbf(a0[i], h, l); ah[s][i] = h;     al[s][i] = l;
                splitbf(a1[i], h, l); ah[s][i + 4] = h; al[s][i + 4] = l;
                splitbf(b0[i], h, l); bh[s][i] = h;     bl[s][i] = l;
                splitbf(b1[i], h, l); bh[s][i + 4] = h; bl[s][i + 4] = l;
            }
        }
    }

    // ---- retention weights: wts = mean(qk(x)) + 0.25*mean(qk(A)) + 0.0625*mean(qk(B)) ----
    f32x4 wts;
    {
        f32x4 kx = {0,0,0,0}, qx = {0,0,0,0};
        f32x4 ka = {0,0,0,0}, qa = {0,0,0,0};
        f32x4 kb = {0,0,0,0}, qb = {0,0,0,0};
        const short* Kp = wbf + WB_K + n * 128 + q * 8;
        const short* Qp = wbf + WB_Q + n * 128 + q * 8;
        #pragma unroll
        for (int s = 0; s < 4; ++s) {
            bf16x8 bkh = *(const bf16x8*)(Kp + s * 32);
            bf16x8 bkl = *(const bf16x8*)(Kp + WB_LO_KQ + s * 32);
            bf16x8 bqh = *(const bf16x8*)(Qp + s * 32);
            bf16x8 bql = *(const bf16x8*)(Qp + WB_LO_KQ + s * 32);
            kx = MFMA(xh[s], bkh, kx); kx = MFMA(xh[s], bkl, kx); kx = MFMA(xl[s], bkh, kx);
            qx = MFMA(xh[s], bqh, qx); qx = MFMA(xh[s], bql, qx); qx = MFMA(xl[s], bqh, qx);
            ka = MFMA(ah[s], bkh, ka); ka = MFMA(ah[s], bkl, ka); ka = MFMA(al[s], bkh, ka);
            qa = MFMA(ah[s], bqh, qa); qa = MFMA(ah[s], bql, qa); qa = MFMA(al[s], bqh, qa);
            kb = MFMA(bh[s], bkh, kb); kb = MFMA(bh[s], bkl, kb); kb = MFMA(bl[s], bkh, kb);
            qb = MFMA(bh[s], bqh, qb); qb = MFMA(bh[s], bql, qb); qb = MFMA(bl[s], bqh, qb);
        }
        #pragma unroll
        for (int r = 0; r < 4; ++r) {
            float p = kx[r] * qx[r] + 0.25f * (ka[r] * qa[r]) + 0.0625f * (kb[r] * qb[r]);
            p += __shfl_xor(p, 1);
            p += __shfl_xor(p, 2);
            p += __shfl_xor(p, 4);
            p += __shfl_xor(p, 8);
            wts[r] = p * (1.f / 16.f);
        }
    }

    // ---- SAGE: S = silu(x@W0 + b + A@W1) ----
    f32x4 S[8];
    #pragma unroll
    for (int t = 0; t < 8; ++t) {
        float bv = sage_b[t * 16 + n];
        S[t] = (f32x4){bv, bv, bv, bv};
    }
    #pragma unroll
    for (int s = 0; s < 4; ++s) {
        #pragma unroll
        for (int t = 0; t < 8; ++t) {
            const short* p0 = wbf + WB_W0 + (t * 16 + n) * 128 + s * 32 + q * 8;
            bf16x8 w0h = *(const bf16x8*)p0;
            bf16x8 w0l = *(const bf16x8*)(p0 + WB_LO_BIG);
            S[t] = MFMA(xh[s], w0h, S[t]);
            S[t] = MFMA(xh[s], w0l, S[t]);
            S[t] = MFMA(xl[s], w0h, S[t]);
            const short* p1 = wbf + WB_W1 + (t * 16 + n) * 128 + s * 32 + q * 8;
            bf16x8 w1h = *(const bf16x8*)p1;
            bf16x8 w1l = *(const bf16x8*)(p1 + WB_LO_BIG);
            S[t] = MFMA(ah[s], w1h, S[t]);
            S[t] = MFMA(ah[s], w1l, S[t]);
            S[t] = MFMA(al[s], w1h, S[t]);
        }
    }
    #pragma unroll
    for (int t = 0; t < 8; ++t)
        #pragma unroll
        for (int r = 0; r < 4; ++r) {
            float v = S[t][r];
            S[t][r] = v / (1.f + __expf(-v));
        }

    // ---- value: V = (c @ Wv) * wts, LN -> attn; Z = S + attn -> global ----
    {
        bf16x8 ch[4], cl[4];
        #pragma unroll
        for (int s = 0; s < 4; ++s)
            #pragma unroll
            for (int i = 0; i < 4; ++i) {
                short h, l;
                splitbf(c0v[s][i], h, l); ch[s][i] = h;     cl[s][i] = l;
                splitbf(c1v[s][i], h, l); ch[s][i + 4] = h; cl[s][i + 4] = l;
            }
        f32x4 V[8];
        #pragma unroll
        for (int t = 0; t < 8; ++t) V[t] = (f32x4){0.f, 0.f, 0.f, 0.f};
        #pragma unroll
        for (int s = 0; s < 4; ++s)
            #pragma unroll
            for (int t = 0; t < 8; ++t) {
                const short* pv = wbf + WB_WV + (t * 16 + n) * 128 + s * 32 + q * 8;
                bf16x8 wvh = *(const bf16x8*)pv;
                bf16x8 wvl = *(const bf16x8*)(pv + WB_LO_BIG);
                V[t] = MFMA(ch[s], wvh, V[t]);
                V[t] = MFMA(ch[s], wvl, V[t]);
                V[t] = MFMA(cl[s], wvh, V[t]);
            }
        f32x4 s1 = {0,0,0,0}, s2 = {0,0,0,0};
        #pragma unroll
        for (int t = 0; t < 8; ++t)
            #pragma unroll
            for (int r = 0; r < 4; ++r) {
                float v = V[t][r] * wts[r];
                V[t][r] = v;
                s1[r] += v; s2[r] += v * v;
            }
        #pragma unroll
        for (int r = 0; r < 4; ++r) {
            float a1 = s1[r], a2 = s2[r];
            a1 += __shfl_xor(a1, 1); a2 += __shfl_xor(a2, 1);
            a1 += __shfl_xor(a1, 2); a2 += __shfl_xor(a2, 2);
            a1 += __shfl_xor(a1, 4); a2 += __shfl_xor(a2, 4);
            a1 += __shfl_xor(a1, 8); a2 += __shfl_xor(a2, 8);
            s1[r] = a1; s2[r] = a2;
        }
        #pragma unroll
        for (int t = 0; t < 8; ++t) {
            float g = attn_g[t * 16 + n];
            float bb = attn_b[t * 16 + n];
            #pragma unroll
            for (int r = 0; r < 4; ++r) {
                float mu = s1[r] * (1.f / 128.f);
                float var = s2[r] * (1.f / 128.f) - mu * mu;
                float rs = rsqrtf(var + EPS_LN);
                float attn = (V[t][r] - mu) * rs * g + bb;
                size_t row = (size_t)blockIdx.x * 64 + w * 16 + q * 4 + r;
                Z[row * 128 + t * 16 + n] = S[t][r] + attn;
            }
        }
    }
}

// ============ dense stage, kernel 2: out = LN(silu(Z@Wl + bl)) ============
__global__ __launch_bounds__(256) void k_dense2(
    const float* __restrict__ Z, const short* __restrict__ wbf,
    const float* __restrict__ lin_b,
    const float* __restrict__ ln_g, const float* __restrict__ ln_b,
    float* __restrict__ out)
{
    const int tid = threadIdx.x;
    const int w = tid >> 6;
    const int lane = tid & 63;
    const int n = lane & 15;
    const int q = lane >> 4;
    const size_t rowA = (size_t)blockIdx.x * 64 + w * 16 + n;

    bf16x8 zh[4], zl[4];
    {
        const float* zp = Z + rowA * 128 + q * 8;
        #pragma unroll
        for (int s = 0; s < 4; ++s) {
            f32x4 z0 = *(const f32x4*)(zp + s * 32);
            f32x4 z1 = *(const f32x4*)(zp + s * 32 + 4);
            #pragma unroll
            for (int i = 0; i < 4; ++i) {
                short h, l;
                splitbf(z0[i], h, l); zh[s][i] = h;     zl[s][i] = l;
                splitbf(z1[i], h, l); zh[s][i + 4] = h; zl[s][i + 4] = l;
            }
        }
    }
    f32x4 F[8];
    #pragma unroll
    for (int t = 0; t < 8; ++t) {
        float bv = lin_b[t * 16 + n];
        F[t] = (f32x4){bv, bv, bv, bv};
    }
    #pragma unroll
    for (int s = 0; s < 4; ++s)
        #pragma unroll
        for (int t = 0; t < 8; ++t) {
            const short* pl = wbf + WB_WL + (t * 16 + n) * 128 + s * 32 + q * 8;
            bf16x8 wlh = *(const bf16x8*)pl;
            bf16x8 wll = *(const bf16x8*)(pl + WB_LO_BIG);
            F[t] = MFMA(zh[s], wlh, F[t]);
            F[t] = MFMA(zh[s], wll, F[t]);
            F[t] = MFMA(zl[s], wlh, F[t]);
        }
    f32x4 s1 = {0,0,0,0}, s2 = {0,0,0,0};
    #pragma unroll
    for (int t = 0; t < 8; ++t)
        #pragma unroll
        for (int r = 0; r < 4; ++r) {
            float v = F[t][r];
            v = v / (1.f + __expf(-v));
            F[t][r] = v;
            s1[r] += v; s2[r] += v * v;
        }
    #pragma unroll
    for (int r = 0; r < 4; ++r) {
        float a1 = s1[r], a2 = s2[r];
        a1 += __shfl_xor(a1, 1); a2 += __shfl_xor(a2, 1);
        a1 += __shfl_xor(a1, 2); a2 += __shfl_xor(a2, 2);
        a1 += __shfl_xor(a1, 4); a2 += __shfl_xor(a2, 4);
        a1 += __shfl_xor(a1, 8); a2 += __shfl_xor(a2, 8);
        s1[r] = a1; s2[r] = a2;
    }
    #pragma unroll
    for (int t = 0; t < 8; ++t) {
        float g = ln_g[t * 16 + n];
        float bb = ln_b[t * 16 + n];
        #pragma unroll
        for (int r = 0; r < 4; ++r) {
            float mu = s1[r] * (1.f / 128.f);
            float var = s2[r] * (1.f / 128.f) - mu * mu;
            float rs = rsqrtf(var + EPS_LN);
            size_t row = (size_t)blockIdx.x * 64 + w * 16 + q * 4 + r;
            out[row * 128 + t * 16 + n] = (F[t][r] - mu) * rs * g + bb;
        }
    }
}

extern "C" void kernel_launch(void* const* d_in, const int* in_sizes, int n_in,
                              void* d_out, int out_size, void* d_ws, size_t ws_size,
                              hipStream_t stream) {
    const float* x       = (const float*)d_in[0];
    const int*   erows   = (const int*)d_in[1];
    const int*   ecols   = (const int*)d_in[2];
    const float* evals   = (const float*)d_in[3];
    const float* sage_W  = (const float*)d_in[4];
    const float* sage_b  = (const float*)d_in[5];
    const float* sage_aW = (const float*)d_in[6];
    const float* key_W   = (const float*)d_in[7];
    const float* query_W = (const float*)d_in[8];
    const float* value_W = (const float*)d_in[9];
    const float* attn_g  = (const float*)d_in[10];
    const float* attn_b  = (const float*)d_in[11];
    const float* lin_W   = (const float*)d_in[12];
    const float* lin_b   = (const float*)d_in[13];
    const float* ln_g    = (const float*)d_in[14];
    const float* ln_b    = (const float*)d_in[15];
    float* out = (float*)d_out;

    int*   wsi = (int*)d_ws;
    float* wsf = (float*)d_ws;
    int*   cnt      = wsi + OFF_CNT;
    int*   row_ptr  = wsi + OFF_ROWPTR;
    int*   row_ofs  = wsi + OFF_ROWOFS;
    int*   csr_cols = wsi + OFF_CCOLS;
    float* csr_vals = wsf + OFF_CVALS;
    short* wbf      = (short*)(wsf + OFF_WBF);
    float* A        = wsf + OFF_A;
    float* B        = wsf + OFF_B;
    float* Zb       = wsf + OFF_Z;

    // CSR build + weight prep (every call; ws is re-poisoned before timed launches)
    hipMemsetAsync(cnt, 0, NN * sizeof(int), stream);
    k_hist<<<(EE + 255) / 256, 256, 0, stream>>>(erows, cnt);
    k_prep<<<(WB_LOGICAL + 255) / 256, 256, 0, stream>>>(sage_W, sage_aW, value_W, lin_W,
                                                         key_W, query_W, wbf);
    k_scan<<<1, 1024, 0, stream>>>(cnt, row_ptr, row_ofs);
    k_scatter<<<(EE + 255) / 256, 256, 0, stream>>>(erows, ecols, evals, row_ofs, csr_cols, csr_vals);

    // A = spmm(x); B = spmm(A)
    k_spmm<<<NN, 128, 0, stream>>>(x, row_ptr, csr_cols, csr_vals, A);
    k_spmm<<<NN, 128, 0, stream>>>(A, row_ptr, csr_cols, csr_vals, B);

    // dense stage (split-bf16 MFMA ~ fp32 precision), two kernels
    k_dense1<<<ROWS / 64, 256, 0, stream>>>(x, A, B, wbf, sage_b, attn_g, attn_b, Zb);
    k_dense2<<<ROWS / 64, 256, 0, stream>>>(Zb, wbf, lin_b, ln_g, ln_b, out);
}

// Round 6
// 701.251 us; speedup vs baseline: 1.6135x; 1.2219x over previous
//
#include <hip/hip_runtime.h>
#include <math.h>

#define LL 4
#define NN 40000
#define DD 128
#define EE 320000
#define ROWS (LL*NN)         // 160000
#define ND (NN*DD)           // 5120000
#define EPS_LN 1e-5f

typedef __attribute__((ext_vector_type(8))) short bf16x8;
typedef __attribute__((ext_vector_type(4))) float f32x4;

// ---------------- workspace layout (units of 4 bytes) ----------------
#define OFF_CNT      0                         // NN ints
#define OFF_ROWPTR   40000                     // NN+1
#define OFF_ROWOFS   80004                     // NN
#define OFF_CCOLS    120004                    // EE
#define OFF_CVALS    440004                    // EE
#define OFF_WBF      760004                    // bf16 hi/lo weights (139264 shorts)
#define OFF_A        829636                    // ROWS*DD floats (16B aligned)
#define OFF_B        (OFF_A + ROWS*DD)
#define OFF_Z        (OFF_B + ROWS*DD)         // ROWS*DD floats

// weight sub-offsets in SHORTS within WBF region. Each big matrix: 16384 hi then 16384 lo.
#define WB_W0  0        // sage_W^T      [n][k] 128x128
#define WB_W1  32768    // sage_agg_W^T
#define WB_WV  65536    // value_W^T
#define WB_WL  98304    // lin_W^T
#define WB_K   131072   // key_W^T   [16][128]: 2048 hi then 2048 lo
#define WB_Q   135168   // query_W^T
#define WB_LO_BIG 16384
#define WB_LO_KQ  2048
#define WB_LOGICAL 69632

__device__ __forceinline__ unsigned fu(float f) { union { float f; unsigned u; } v; v.f = f; return v.u; }
__device__ __forceinline__ float uf(unsigned u) { union { unsigned u; float f; } v; v.u = u; return v.f; }

__device__ __forceinline__ short f2bf(float f) {           // RNE (used in prep only)
    unsigned u = fu(f);
    unsigned r = u + 0x7fffu + ((u >> 16) & 1u);
    return (short)(r >> 16);
}
__device__ __forceinline__ float bf2f(short h) { return uf(((unsigned)(unsigned short)h) << 16); }
__device__ __forceinline__ void splitbf(float v, short& h, short& l) {  // prep only
    h = f2bf(v);
    l = f2bf(v - bf2f(h));
}

// truncation pack: two floats -> one VGPR of 2 bf16 (lo short = a, hi short = b)
__device__ __forceinline__ unsigned pack_hi(float a, float b) {
    return (fu(a) >> 16) | (fu(b) & 0xffff0000u);
}
// truncation residual
__device__ __forceinline__ float resid(float a) {
    return a - uf(fu(a) & 0xffff0000u);
}

union FragU { bf16x8 v; unsigned u[4]; };

// ---------------- CSR build ----------------
__global__ void k_hist(const int* __restrict__ rows, int* __restrict__ cnt) {
    int e = blockIdx.x * 256 + threadIdx.x;
    if (e < EE) atomicAdd(&cnt[rows[e]], 1);
}

__global__ __launch_bounds__(1024) void k_scan(const int* __restrict__ cnt,
                                               int* __restrict__ row_ptr,
                                               int* __restrict__ row_ofs) {
    __shared__ int wtot[16];
    __shared__ int s_carry;
    int tid = threadIdx.x;
    int lane = tid & 63, wid = tid >> 6;
    if (tid == 0) s_carry = 0;
    __syncthreads();
    for (int base = 0; base <= NN; base += 1024) {
        int i = base + tid;
        int v = (i < NN) ? cnt[i] : 0;
        int incl = v;
        #pragma unroll
        for (int off = 1; off < 64; off <<= 1) {
            int t = __shfl_up(incl, off);
            if (lane >= off) incl += t;
        }
        if (lane == 63) wtot[wid] = incl;
        __syncthreads();
        if (wid == 0) {
            int w = (lane < 16) ? wtot[lane] : 0;
            #pragma unroll
            for (int off = 1; off < 16; off <<= 1) {
                int t = __shfl_up(w, off);
                if (lane >= off) w += t;
            }
            if (lane < 16) wtot[lane] = w;
        }
        __syncthreads();
        int carry = s_carry;
        int wofs = (wid > 0) ? wtot[wid - 1] : 0;
        int excl = carry + wofs + incl - v;
        if (i <= NN) {
            row_ptr[i] = excl;
            if (i < NN) row_ofs[i] = excl;
        }
        __syncthreads();
        if (tid == 0) s_carry = carry + wtot[15];
        __syncthreads();
    }
}

__global__ void k_scatter(const int* __restrict__ rows, const int* __restrict__ cols,
                          const float* __restrict__ vals, int* __restrict__ row_ofs,
                          int* __restrict__ csr_cols, float* __restrict__ csr_vals) {
    int e = blockIdx.x * 256 + threadIdx.x;
    if (e < EE) {
        int r = rows[e];
        int p = atomicAdd(&row_ofs[r], 1);
        csr_cols[p] = cols[e];
        csr_vals[p] = vals[e];
    }
}

// ---------------- SpMM: out[l,r,d] = sum_e vals[e] * in[l,cols[e],d] ----------------
__global__ __launch_bounds__(128) void k_spmm(const float* __restrict__ in,
                                              const int* __restrict__ row_ptr,
                                              const int* __restrict__ ccols,
                                              const float* __restrict__ cvals,
                                              float* __restrict__ out) {
    int r = blockIdx.x;
    int tid = threadIdx.x;
    int l = tid >> 5;
    int d4 = (tid & 31) * 4;
    int ofs = l * ND + d4;
    float4 acc = make_float4(0.f, 0.f, 0.f, 0.f);
    int e0 = row_ptr[r], e1 = row_ptr[r + 1];
    for (int e = e0; e < e1; ++e) {
        int c = ccols[e];
        float v = cvals[e];
        float4 xv = *(const float4*)(in + ofs + c * DD);
        acc.x += v * xv.x; acc.y += v * xv.y; acc.z += v * xv.z; acc.w += v * xv.w;
    }
    *(float4*)(out + ofs + r * DD) = acc;
}

// ---------------- weight prep: fp32 [k][n] -> bf16 hi/lo transposed [n][k] ----------------
__global__ void k_prep(const float* __restrict__ W0, const float* __restrict__ W1,
                       const float* __restrict__ Wv, const float* __restrict__ Wl,
                       const float* __restrict__ Kw, const float* __restrict__ Qw,
                       short* __restrict__ o) {
    int t = blockIdx.x * 256 + threadIdx.x;
    if (t >= WB_LOGICAL) return;
    float v;
    int hi_idx, lo_idx;
    if (t < 65536) {
        int m = t >> 14, idx = t & 16383;
        int nn = idx >> 7, kk = idx & 127;
        const float* M = (m == 0) ? W0 : (m == 1) ? W1 : (m == 2) ? Wv : Wl;
        v = M[kk * 128 + nn];
        hi_idx = m * 32768 + idx;
        lo_idx = hi_idx + WB_LO_BIG;
    } else {
        int t2 = t - 65536;
        int sel = t2 >> 11;
        int idx = t2 & 2047;
        int nn = idx >> 7, kk = idx & 127;
        const float* M = sel ? Qw : Kw;
        v = M[kk * 16 + nn];
        hi_idx = WB_K + sel * 4096 + idx;
        lo_idx = hi_idx + WB_LO_KQ;
    }
    short h, l;
    splitbf(v, h, l);
    o[hi_idx] = h;
    o[lo_idx] = l;
}

// ============ dense stage, kernel 1: qk(split) + sage(hi) + value(hi)(+LN) -> Z ============
// 2500 blocks x 256 (4 waves); wave w owns rows blk*64 + w*16 .. +16.
// MFMA 16x16x32 bf16 (m89-verified):
//   A-frag: lane holds row m=lane&15, k=(lane>>4)*8+j   B-frag: col n=lane&15, same k
//   C/D:    col = lane&15, row = (lane>>4)*4 + reg
// Precision: split-bf16 (hi+lo, trunc) ONLY for the qk path (LN(V*wts) amplifies
// sign(wts); need rel err << 6e-3 there). SAGE/value are hi-only bf16: their error is
// relative (~0.5%) and LN-normalized downstream -> ~0.02-0.05 abs, under the 0.16 bar.
#define MFMA(a, b, c) __builtin_amdgcn_mfma_f32_16x16x32_bf16(a, b, c, 0, 0, 0)

__global__ __launch_bounds__(256) void k_dense1(
    const float* __restrict__ x, const float* __restrict__ A, const float* __restrict__ B,
    const short* __restrict__ wbf,
    const float* __restrict__ sage_b, const float* __restrict__ attn_g,
    const float* __restrict__ attn_b,
    float* __restrict__ Z)
{
    const int tid = threadIdx.x;
    const int w = tid >> 6;
    const int lane = tid & 63;
    const int n = lane & 15;
    const int q = lane >> 4;
    const size_t rowA = (size_t)blockIdx.x * 64 + w * 16 + n;

    bf16x8 xh[4], ah[4], ch[4];          // persistent hi frags (trunc)
    f32x4 kx = {0,0,0,0}, qx = {0,0,0,0};
    f32x4 ka = {0,0,0,0}, qa = {0,0,0,0};
    f32x4 kb = {0,0,0,0}, qb = {0,0,0,0};

    {
        const float* xp = x + rowA * 128 + q * 8;
        const float* ap = A + rowA * 128 + q * 8;
        const float* bp = B + rowA * 128 + q * 8;
        const short* Kp = wbf + WB_K + n * 128 + q * 8;
        const short* Qp = wbf + WB_Q + n * 128 + q * 8;
        #pragma unroll
        for (int s = 0; s < 4; ++s) {
            f32x4 x0 = *(const f32x4*)(xp + s * 32);
            f32x4 x1 = *(const f32x4*)(xp + s * 32 + 4);
            f32x4 a0 = *(const f32x4*)(ap + s * 32);
            f32x4 a1 = *(const f32x4*)(ap + s * 32 + 4);
            f32x4 b0 = *(const f32x4*)(bp + s * 32);
            f32x4 b1 = *(const f32x4*)(bp + s * 32 + 4);
            f32x4 c0 = x0 + 0.5f * a0 + 0.25f * b0;
            f32x4 c1 = x1 + 0.5f * a1 + 0.25f * b1;

            FragU fxh, fxl, fah, fal, fbh, fbl, fch;
            #pragma unroll
            for (int i = 0; i < 2; ++i) {
                fxh.u[i]     = pack_hi(x0[2*i], x0[2*i+1]);
                fxh.u[i + 2] = pack_hi(x1[2*i], x1[2*i+1]);
                fxl.u[i]     = pack_hi(resid(x0[2*i]), resid(x0[2*i+1]));
                fxl.u[i + 2] = pack_hi(resid(x1[2*i]), resid(x1[2*i+1]));
                fah.u[i]     = pack_hi(a0[2*i], a0[2*i+1]);
                fah.u[i + 2] = pack_hi(a1[2*i], a1[2*i+1]);
                fal.u[i]     = pack_hi(resid(a0[2*i]), resid(a0[2*i+1]));
                fal.u[i + 2] = pack_hi(resid(a1[2*i]), resid(a1[2*i+1]));
                fbh.u[i]     = pack_hi(b0[2*i], b0[2*i+1]);
                fbh.u[i + 2] = pack_hi(b1[2*i], b1[2*i+1]);
                fbl.u[i]     = pack_hi(resid(b0[2*i]), resid(b0[2*i+1]));
                fbl.u[i + 2] = pack_hi(resid(b1[2*i]), resid(b1[2*i+1]));
                fch.u[i]     = pack_hi(c0[2*i], c0[2*i+1]);
                fch.u[i + 2] = pack_hi(c1[2*i], c1[2*i+1]);
            }
            xh[s] = fxh.v; ah[s] = fah.v; ch[s] = fch.v;

            bf16x8 bkh = *(const bf16x8*)(Kp + s * 32);
            bf16x8 bkl = *(const bf16x8*)(Kp + WB_LO_KQ + s * 32);
            bf16x8 bqh = *(const bf16x8*)(Qp + s * 32);
            bf16x8 bql = *(const bf16x8*)(Qp + WB_LO_KQ + s * 32);
            // split product: ah.bh + al.bh + ah.bl
            kx = MFMA(fxh.v, bkh, kx); kx = MFMA(fxl.v, bkh, kx); kx = MFMA(fxh.v, bkl, kx);
            qx = MFMA(fxh.v, bqh, qx); qx = MFMA(fxl.v, bqh, qx); qx = MFMA(fxh.v, bql, qx);
            ka = MFMA(fah.v, bkh, ka); ka = MFMA(fal.v, bkh, ka); ka = MFMA(fah.v, bkl, ka);
            qa = MFMA(fah.v, bqh, qa); qa = MFMA(fal.v, bqh, qa); qa = MFMA(fah.v, bql, qa);
            kb = MFMA(fbh.v, bkh, kb); kb = MFMA(fbl.v, bkh, kb); kb = MFMA(fbh.v, bkl, kb);
            qb = MFMA(fbh.v, bqh, qb); qb = MFMA(fbl.v, bqh, qb); qb = MFMA(fbh.v, bql, qb);
        }
    }

    // wts = mean(kx*qx) + 0.25*mean(ka*qa) + 0.0625*mean(kb*qb)   (mean over 16 cols)
    f32x4 wts;
    #pragma unroll
    for (int r = 0; r < 4; ++r) {
        float p = kx[r] * qx[r] + 0.25f * (ka[r] * qa[r]) + 0.0625f * (kb[r] * qb[r]);
        p += __shfl_xor(p, 1);
        p += __shfl_xor(p, 2);
        p += __shfl_xor(p, 4);
        p += __shfl_xor(p, 8);
        wts[r] = p * (1.f / 16.f);
    }

    // ---- SAGE: S = silu(x@W0 + b + A@W1)   (hi-only) ----
    f32x4 S[8];
    #pragma unroll
    for (int t = 0; t < 8; ++t) {
        float bv = sage_b[t * 16 + n];
        S[t] = (f32x4){bv, bv, bv, bv};
    }
    #pragma unroll
    for (int s = 0; s < 4; ++s) {
        #pragma unroll
        for (int t = 0; t < 8; ++t) {
            bf16x8 w0h = *(const bf16x8*)(wbf + WB_W0 + (t * 16 + n) * 128 + s * 32 + q * 8);
            S[t] = MFMA(xh[s], w0h, S[t]);
            bf16x8 w1h = *(const bf16x8*)(wbf + WB_W1 + (t * 16 + n) * 128 + s * 32 + q * 8);
            S[t] = MFMA(ah[s], w1h, S[t]);
        }
    }
    #pragma unroll
    for (int t = 0; t < 8; ++t)
        #pragma unroll
        for (int r = 0; r < 4; ++r) {
            float v = S[t][r];
            S[t][r] = v / (1.f + __expf(-v));
        }

    // ---- value: V = (c @ Wv) * wts, LN -> attn; Z = S + attn -> global ----
    f32x4 V[8];
    #pragma unroll
    for (int t = 0; t < 8; ++t) V[t] = (f32x4){0.f, 0.f, 0.f, 0.f};
    #pragma unroll
    for (int s = 0; s < 4; ++s)
        #pragma unroll
        for (int t = 0; t < 8; ++t) {
            bf16x8 wvh = *(const bf16x8*)(wbf + WB_WV + (t * 16 + n) * 128 + s * 32 + q * 8);
            V[t] = MFMA(ch[s], wvh, V[t]);
        }
    f32x4 s1 = {0,0,0,0}, s2 = {0,0,0,0};
    #pragma unroll
    for (int t = 0; t < 8; ++t)
        #pragma unroll
        for (int r = 0; r < 4; ++r) {
            float v = V[t][r] * wts[r];
            V[t][r] = v;
            s1[r] += v; s2[r] += v * v;
        }
    #pragma unroll
    for (int r = 0; r < 4; ++r) {
        float a1 = s1[r], a2 = s2[r];
        a1 += __shfl_xor(a1, 1); a2 += __shfl_xor(a2, 1);
        a1 += __shfl_xor(a1, 2); a2 += __shfl_xor(a2, 2);
        a1 += __shfl_xor(a1, 4); a2 += __shfl_xor(a2, 4);
        a1 += __shfl_xor(a1, 8); a2 += __shfl_xor(a2, 8);
        s1[r] = a1; s2[r] = a2;
    }
    #pragma unroll
    for (int t = 0; t < 8; ++t) {
        float g = attn_g[t * 16 + n];
        float bb = attn_b[t * 16 + n];
        #pragma unroll
        for (int r = 0; r < 4; ++r) {
            float mu = s1[r] * (1.f / 128.f);
            float var = s2[r] * (1.f / 128.f) - mu * mu;
            float rs = rsqrtf(var + EPS_LN);
            float attn = (V[t][r] - mu) * rs * g + bb;
            size_t row = (size_t)blockIdx.x * 64 + w * 16 + q * 4 + r;
            Z[row * 128 + t * 16 + n] = S[t][r] + attn;
        }
    }
}

// ============ dense stage, kernel 2: out = LN(silu(Z@Wl + bl))  (hi-only) ============
__global__ __launch_bounds__(256) void k_dense2(
    const float* __restrict__ Z, const short* __restrict__ wbf,
    const float* __restrict__ lin_b,
    const float* __restrict__ ln_g, const float* __restrict__ ln_b,
    float* __restrict__ out)
{
    const int tid = threadIdx.x;
    const int w = tid >> 6;
    const int lane = tid & 63;
    const int n = lane & 15;
    const int q = lane >> 4;
    const size_t rowA = (size_t)blockIdx.x * 64 + w * 16 + n;

    bf16x8 zh[4];
    {
        const float* zp = Z + rowA * 128 + q * 8;
        #pragma unroll
        for (int s = 0; s < 4; ++s) {
            f32x4 z0 = *(const f32x4*)(zp + s * 32);
            f32x4 z1 = *(const f32x4*)(zp + s * 32 + 4);
            FragU f;
            #pragma unroll
            for (int i = 0; i < 2; ++i) {
                f.u[i]     = pack_hi(z0[2*i], z0[2*i+1]);
                f.u[i + 2] = pack_hi(z1[2*i], z1[2*i+1]);
            }
            zh[s] = f.v;
        }
    }
    f32x4 F[8];
    #pragma unroll
    for (int t = 0; t < 8; ++t) {
        float bv = lin_b[t * 16 + n];
        F[t] = (f32x4){bv, bv, bv, bv};
    }
    #pragma unroll
    for (int s = 0; s < 4; ++s)
        #pragma unroll
        for (int t = 0; t < 8; ++t) {
            bf16x8 wlh = *(const bf16x8*)(wbf + WB_WL + (t * 16 + n) * 128 + s * 32 + q * 8);
            F[t] = MFMA(zh[s], wlh, F[t]);
        }
    f32x4 s1 = {0,0,0,0}, s2 = {0,0,0,0};
    #pragma unroll
    for (int t = 0; t < 8; ++t)
        #pragma unroll
        for (int r = 0; r < 4; ++r) {
            float v = F[t][r];
            v = v / (1.f + __expf(-v));
            F[t][r] = v;
            s1[r] += v; s2[r] += v * v;
        }
    #pragma unroll
    for (int r = 0; r < 4; ++r) {
        float a1 = s1[r], a2 = s2[r];
        a1 += __shfl_xor(a1, 1); a2 += __shfl_xor(a2, 1);
        a1 += __shfl_xor(a1, 2); a2 += __shfl_xor(a2, 2);
        a1 += __shfl_xor(a1, 4); a2 += __shfl_xor(a2, 4);
        a1 += __shfl_xor(a1, 8); a2 += __shfl_xor(a2, 8);
        s1[r] = a1; s2[r] = a2;
    }
    #pragma unroll
    for (int t = 0; t < 8; ++t) {
        float g = ln_g[t * 16 + n];
        float bb = ln_b[t * 16 + n];
        #pragma unroll
        for (int r = 0; r < 4; ++r) {
            float mu = s1[r] * (1.f / 128.f);
            float var = s2[r] * (1.f / 128.f) - mu * mu;
            float rs = rsqrtf(var + EPS_LN);
            size_t row = (size_t)blockIdx.x * 64 + w * 16 + q * 4 + r;
            out[row * 128 + t * 16 + n] = (F[t][r] - mu) * rs * g + bb;
        }
    }
}

extern "C" void kernel_launch(void* const* d_in, const int* in_sizes, int n_in,
                              void* d_out, int out_size, void* d_ws, size_t ws_size,
                              hipStream_t stream) {
    const float* x       = (const float*)d_in[0];
    const int*   erows   = (const int*)d_in[1];
    const int*   ecols   = (const int*)d_in[2];
    const float* evals   = (const float*)d_in[3];
    const float* sage_W  = (const float*)d_in[4];
    const float* sage_b  = (const float*)d_in[5];
    const float* sage_aW = (const float*)d_in[6];
    const float* key_W   = (const float*)d_in[7];
    const float* query_W = (const float*)d_in[8];
    const float* value_W = (const float*)d_in[9];
    const float* attn_g  = (const float*)d_in[10];
    const float* attn_b  = (const float*)d_in[11];
    const float* lin_W   = (const float*)d_in[12];
    const float* lin_b   = (const float*)d_in[13];
    const float* ln_g    = (const float*)d_in[14];
    const float* ln_b    = (const float*)d_in[15];
    float* out = (float*)d_out;

    int*   wsi = (int*)d_ws;
    float* wsf = (float*)d_ws;
    int*   cnt      = wsi + OFF_CNT;
    int*   row_ptr  = wsi + OFF_ROWPTR;
    int*   row_ofs  = wsi + OFF_ROWOFS;
    int*   csr_cols = wsi + OFF_CCOLS;
    float* csr_vals = wsf + OFF_CVALS;
    short* wbf      = (short*)(wsf + OFF_WBF);
    float* A        = wsf + OFF_A;
    float* B        = wsf + OFF_B;
    float* Zb       = wsf + OFF_Z;

    // CSR build + weight prep (every call; ws is re-poisoned before timed launches)
    hipMemsetAsync(cnt, 0, NN * sizeof(int), stream);
    k_hist<<<(EE + 255) / 256, 256, 0, stream>>>(erows, cnt);
    k_prep<<<(WB_LOGICAL + 255) / 256, 256, 0, stream>>>(sage_W, sage_aW, value_W, lin_W,
                                                         key_W, query_W, wbf);
    k_scan<<<1, 1024, 0, stream>>>(cnt, row_ptr, row_ofs);
    k_scatter<<<(EE + 255) / 256, 256, 0, stream>>>(erows, ecols, evals, row_ofs, csr_cols, csr_vals);

    // A = spmm(x); B = spmm(A)
    k_spmm<<<NN, 128, 0, stream>>>(x, row_ptr, csr_cols, csr_vals, A);
    k_spmm<<<NN, 128, 0, stream>>>(A, row_ptr, csr_cols, csr_vals, B);

    // dense stage: split-bf16 only on the qk path, hi-only elsewhere
    k_dense1<<<ROWS / 64, 256, 0, stream>>>(x, A, B, wbf, sage_b, attn_g, attn_b, Zb);
    k_dense2<<<ROWS / 64, 256, 0, stream>>>(Zb, wbf, lin_b, ln_g, ln_b, out);
}